// Round 8
// baseline (14673.846 us; speedup 1.0000x reference)
//
#include <hip/hip_runtime.h>
#include <hip/hip_cooperative_groups.h>
#include <math.h>

namespace cg = cooperative_groups;

#define B 128
#define N 1000
#define NP 1024
#define D 128
#define STEPS 64
#define TASKS 1024
#define RPT 125                  // rows per (b,g) task; 8*125 = 1000
#define NEG_INF (-INFINITY)
#define OUT_NEG (-1.0e30f)       // finite stand-in for -inf in OUTPUT only

// ---------------- ws float-offsets ----------------
#define OFF_FIXED   0                          // B*D
#define OFF_FCPART  (OFF_FIXED + B*D)          // B*8*D
#define OFF_ME      (OFF_FCPART + B*8*D)       // B*8*8
#define OFF_SE      (OFF_ME + B*8*8)           // B*8*8
#define OFF_WAE     (OFF_SE + B*8*8)           // B*8*1024
#define OFF_LV      (OFF_WAE + B*8*1024)       // B*NP
#define OFF_AM      (OFF_LV + B*NP)            // B*8
#define OFF_AS      (OFF_AM + B*8)             // B*8
#define OFF_FIRST   (OFF_AS + B*8)             // B*D
#define OFF_PREV    (OFF_FIRST + B*D)          // B*D
#define OFF_INT     (OFF_PREV + B*D)           // ints: aI B*8, visited B*NP

__global__ void __launch_bounds__(256)
decode_coop(const float* __restrict__ emb, const float* __restrict__ Wn,
            const float* __restrict__ Wf, const float* __restrict__ Wstep,
            const float* __restrict__ Wout, const float* __restrict__ Wp,
            float* __restrict__ out, float* __restrict__ ws) {
  cg::grid_group gg = cg::this_grid();

  float* fixed_ctx = ws + OFF_FIXED;
  float* fcPart    = ws + OFF_FCPART;
  float* mE        = ws + OFF_ME;
  float* sE        = ws + OFF_SE;
  float* waE       = ws + OFF_WAE;
  float* lv        = ws + OFF_LV;
  float* aM        = ws + OFF_AM;
  float* aS        = ws + OFF_AS;
  float* first_emb = ws + OFF_FIRST;
  float* prev_emb  = ws + OFF_PREV;
  int*   aI        = (int*)(ws + OFF_INT);
  int*   visited   = aI + B * 8;

  const int t = threadIdx.x;
  const int lane = t & 63, wv = t >> 6;
  const int r = (lane >> 4) & 3, c = lane & 15;
  const int G = gridDim.x;

  // 25.5 KB LDS pool, carved per phase (phases separated by syncs)
  __shared__ float lds[6528];
  // phase A carve
  float* ctxL = lds;          // 256
  float* qL   = lds + 256;    // 128
  float* qkL  = lds + 384;    // 8*128
  float* cB   = lds + 1408;   // 8*128  compat -> p
  float* waW  = lds + 2432;   // 4*1024 wave partials
  float* redA = lds + 384;    // reuse qkL tail? NO -- qkL live. use dedicated:
  // (redA not used; per-head m/s go in mhL/shL below, carved past waW? pool full)
  __shared__ float mhL[8];
  __shared__ float shL[8];
  // phase B carve (reuses pool)
  float* fH     = lds;           // 8*8 [g][h]
  float* invS   = lds + 64;      // 8
  float* weNl   = lds + 128;     // 8*128
  float* headsL = lds + 1152;    // 128
  float* glL    = lds + 1280;    // 128
  float* lqL    = lds + 1408;    // 128
  float* lvL    = lds + 1536;    // 128
  float* redF   = lds + 1664;    // 8
  int*   redIi  = (int*)(lds + 1672); // 2
  // phase C carve
  float* aML = lds;        // 8
  float* aSL = lds + 8;    // 8
  int*   aIL = (int*)(lds + 16); // 8

  const float4* emb4 = (const float4*)emb;

  // ---------------- prologue: zero visited, fcPart ----------------
  for (int i = blockIdx.x * 256 + t; i < B * NP; i += G * 256) visited[i] = 0;
  for (int task = blockIdx.x; task < TASKS; task += G) {
    int b = task >> 3, g = task & 7;
    int d = t & 127, half = t >> 7;
    float s = 0.f;
    for (int i = half; i < RPT; i += 2)
      s += emb[((size_t)b * N + g * RPT + i) * D + d];
    __syncthreads();
    ctxL[t] = s;
    __syncthreads();
    if (t < 128) fcPart[(size_t)task * 128 + t] = ctxL[t] + ctxL[t + 128];
  }
  gg.sync();
  for (int task = blockIdx.x; task < B; task += G) {
    __syncthreads();
    if (t < 128) {
      float s = 0.f;
      for (int g = 0; g < 8; ++g) s += fcPart[(size_t)(task * 8 + g) * 128 + t];
      ctxL[t] = s * (1.0f / 1000.0f);
    }
    __syncthreads();
    if (t < 128) {
      float a = 0.f;
      for (int k = 0; k < 128; ++k) a += ctxL[k] * Wf[k * 128 + t];
      fixed_ctx[task * 128 + t] = a;
    }
  }
  gg.sync();

  // ---------------- decode loop ----------------
  for (int step = 0; step < STEPS; ++step) {
    // ======== PHASE A: glimpse partials per (b,g) ========
    for (int task = blockIdx.x; task < TASKS; task += G) {
      int b = task >> 3, g = task & 7, n0 = g * RPT;
      __syncthreads();
      {
        float v;
        if (step == 0) v = Wp[t];
        else v = (t < 128) ? first_emb[b * 128 + t] : prev_emb[b * 128 + (t - 128)];
        ctxL[t] = v;
      }
      __syncthreads();
      if (t < 128) {
        float a = fixed_ctx[b * 128 + t];
        for (int i = 0; i < 256; ++i) a += ctxL[i] * Wstep[i * 128 + t];
        qL[t] = a;
      }
      __syncthreads();
      {
        int d = t >> 1, h0 = (t & 1) * 4;
#pragma unroll
        for (int u = 0; u < 4; ++u) {
          int hh = h0 + u;
          float a = 0.f;
#pragma unroll
          for (int k = 0; k < 16; ++k) a += qL[hh * 16 + k] * Wn[(size_t)d * 384 + hh * 16 + k];
          qkL[hh * 128 + d] = a * 0.25f;   // 1/sqrt(dk)
        }
      }
      __syncthreads();
      // pass 1: compat -> cB (padded nl in [125,128) -> NEG_INF)
      {
        float qkr[8][8];
#pragma unroll
        for (int h = 0; h < 8; ++h)
#pragma unroll
          for (int j = 0; j < 8; ++j) qkr[h][j] = qkL[h * 128 + c * 8 + j];
        for (int it = 0; it < 8; ++it) {
          int nl = it * 16 + wv * 4 + r;
          bool inb = (nl < RPT);
          int n = n0 + nl;
          float4 e0 = make_float4(0.f, 0.f, 0.f, 0.f), e1 = e0;
          if (inb) {
            e0 = emb4[((size_t)b * N + n) * 32 + c * 2];
            e1 = emb4[((size_t)b * N + n) * 32 + c * 2 + 1];
          }
          float s[8];
#pragma unroll
          for (int h = 0; h < 8; ++h) {
            s[h] = qkr[h][0] * e0.x + qkr[h][1] * e0.y + qkr[h][2] * e0.z + qkr[h][3] * e0.w
                 + qkr[h][4] * e1.x + qkr[h][5] * e1.y + qkr[h][6] * e1.z + qkr[h][7] * e1.w;
          }
#pragma unroll
          for (int off = 1; off <= 8; off <<= 1)
#pragma unroll
            for (int h = 0; h < 8; ++h) s[h] += __shfl_xor(s[h], off);
          if (c == 0) {
            bool vis = !inb || (visited[b * NP + n] != 0);
#pragma unroll
            for (int h = 0; h < 8; ++h) cB[h * 128 + nl] = vis ? NEG_INF : s[h];
          }
        }
      }
      __syncthreads();
      // per-head max
#pragma unroll
      for (int u = 0; u < 2; ++u) {
        int h = wv * 2 + u;
        float m = fmaxf(cB[h * 128 + lane], cB[h * 128 + lane + 64]);
#pragma unroll
        for (int off = 1; off <= 32; off <<= 1) m = fmaxf(m, __shfl_xor(m, off));
        if (lane == 0) mhL[h] = m;
      }
      __syncthreads();
      // exp in place
#pragma unroll
      for (int u = 0; u < 4; ++u) {
        int idx = t + u * 256;
        float v = cB[idx];
        cB[idx] = (v == NEG_INF) ? 0.f : expf(v - mhL[idx >> 7]);
      }
      __syncthreads();
      // per-head sum
#pragma unroll
      for (int u = 0; u < 2; ++u) {
        int h = wv * 2 + u;
        float s = cB[h * 128 + lane] + cB[h * 128 + lane + 64];
#pragma unroll
        for (int off = 1; off <= 32; off <<= 1) s += __shfl_xor(s, off);
        if (lane == 0) shL[h] = s;
      }
      // pass 2: weighted emb accumulate
      {
        float wa[8][8];
#pragma unroll
        for (int h = 0; h < 8; ++h)
#pragma unroll
          for (int j = 0; j < 8; ++j) wa[h][j] = 0.f;
        for (int it = 0; it < 8; ++it) {
          int nl = it * 16 + wv * 4 + r;
          if (nl < RPT) {
            int n = n0 + nl;
            float4 e0 = emb4[((size_t)b * N + n) * 32 + c * 2];
            float4 e1 = emb4[((size_t)b * N + n) * 32 + c * 2 + 1];
#pragma unroll
            for (int h = 0; h < 8; ++h) {
              float p = cB[h * 128 + nl];
              wa[h][0] += p * e0.x; wa[h][1] += p * e0.y;
              wa[h][2] += p * e0.z; wa[h][3] += p * e0.w;
              wa[h][4] += p * e1.x; wa[h][5] += p * e1.y;
              wa[h][6] += p * e1.z; wa[h][7] += p * e1.w;
            }
          }
        }
#pragma unroll
        for (int h = 0; h < 8; ++h)
#pragma unroll
          for (int j = 0; j < 8; ++j) {
            wa[h][j] += __shfl_xor(wa[h][j], 16);
            wa[h][j] += __shfl_xor(wa[h][j], 32);
          }
        if (lane < 16) {
#pragma unroll
          for (int h = 0; h < 8; ++h)
#pragma unroll
            for (int j = 0; j < 8; ++j) waW[wv * 1024 + h * 128 + c * 8 + j] = wa[h][j];
        }
      }
      __syncthreads();
#pragma unroll
      for (int u = 0; u < 4; ++u) {
        int idx = t + u * 256;
        waE[(size_t)task * 1024 + idx] =
            waW[idx] + waW[1024 + idx] + waW[2048 + idx] + waW[3072 + idx];
      }
      if (t < 8) { mE[task * 8 + t] = mhL[t]; sE[task * 8 + t] = shL[t]; }
    }
    gg.sync();

    // ======== PHASE B: merge -> lq -> logits partials per (b,g) ========
    for (int task = blockIdx.x; task < TASKS; task += G) {
      int b = task >> 3, g = task & 7, n0 = g * RPT;
      __syncthreads();
      if (t < 8) {
        float M = NEG_INF;
        for (int g2 = 0; g2 < 8; ++g2) M = fmaxf(M, mE[(b * 8 + g2) * 8 + t]);
        float S = 0.f;
        for (int g2 = 0; g2 < 8; ++g2) {
          float f = expf(mE[(b * 8 + g2) * 8 + t] - M);
          fH[g2 * 8 + t] = f;
          S += sE[(b * 8 + g2) * 8 + t] * f;
        }
        invS[t] = 1.0f / S;
      }
      __syncthreads();
      for (int idx = t; idx < 1024; idx += 256) {
        int h = idx >> 7;
        float w = 0.f;
        for (int g2 = 0; g2 < 8; ++g2)
          w += waE[(size_t)(b * 8 + g2) * 1024 + idx] * fH[g2 * 8 + h];
        weNl[idx] = w * invS[h];
      }
      __syncthreads();
      if (t < 128) {
        int h = t >> 4;
        float a = 0.f;
        for (int d = 0; d < 128; ++d) a += weNl[h * 128 + d] * Wn[(size_t)d * 384 + 128 + t];
        headsL[t] = a;
      }
      __syncthreads();
      if (t < 128) {
        float a = 0.f;
        for (int k = 0; k < 128; ++k) a += headsL[k] * Wout[k * 128 + t];
        glL[t] = a;
      }
      __syncthreads();
      if (t < 128) {
        float a = 0.f;
        for (int e = 0; e < 128; ++e) a += glL[e] * Wn[(size_t)t * 384 + 256 + e];
        lqL[t] = a * 0.08838834764831845f;   // 1/sqrt(128)
      }
      __syncthreads();
      // logits rows
      {
        float lq0[8];
#pragma unroll
        for (int j = 0; j < 8; ++j) lq0[j] = lqL[c * 8 + j];
        for (int it = 0; it < 8; ++it) {
          int nl = it * 16 + wv * 4 + r;
          bool inb = (nl < RPT);
          int n = n0 + nl;
          float4 e0 = make_float4(0.f, 0.f, 0.f, 0.f), e1 = e0;
          if (inb) {
            e0 = emb4[((size_t)b * N + n) * 32 + c * 2];
            e1 = emb4[((size_t)b * N + n) * 32 + c * 2 + 1];
          }
          float s = lq0[0] * e0.x + lq0[1] * e0.y + lq0[2] * e0.z + lq0[3] * e0.w
                  + lq0[4] * e1.x + lq0[5] * e1.y + lq0[6] * e1.z + lq0[7] * e1.w;
#pragma unroll
          for (int off = 1; off <= 8; off <<= 1) s += __shfl_xor(s, off);
          if (c == 0) {
            bool vis = !inb || (visited[b * NP + n] != 0);
            lvL[nl] = vis ? NEG_INF : 10.f * tanhf(s);
          }
        }
      }
      __syncthreads();
      // lv write + per-task max/argmax/sumexp partials
      {
        float v = (t < 128) ? lvL[t] : NEG_INF;
        if (t < RPT) lv[b * NP + n0 + t] = v;
        if (t < 128) {
          float bv = v; int bi = n0 + t;
#pragma unroll
          for (int off = 32; off >= 1; off >>= 1) {
            float ov = __shfl_xor(bv, off);
            int oi = __shfl_xor(bi, off);
            if (ov > bv || (ov == bv && oi < bi)) { bv = ov; bi = oi; }
          }
          if (lane == 0) { redF[wv] = bv; redIi[wv] = bi; }
        }
        __syncthreads();
        float Mt = redF[0]; int It = redIi[0];
        if (redF[1] > Mt || (redF[1] == Mt && redIi[1] < It)) { Mt = redF[1]; It = redIi[1]; }
        if (t < 128) {
          float se = (v == NEG_INF) ? 0.f : expf(v - Mt);
#pragma unroll
          for (int off = 1; off <= 32; off <<= 1) se += __shfl_xor(se, off);
          if (lane == 0) redF[4 + wv] = se;
        }
        __syncthreads();
        if (t == 0) { aM[task] = Mt; aS[task] = redF[4] + redF[5]; aI[task] = It; }
      }
    }
    gg.sync();

    // ======== PHASE C: finalize per (b,g) ========
    for (int task = blockIdx.x; task < TASKS; task += G) {
      int b = task >> 3, g = task & 7, n0 = g * RPT;
      __syncthreads();
      if (t < 8) { aML[t] = aM[b * 8 + t]; aSL[t] = aS[b * 8 + t]; aIL[t] = aI[b * 8 + t]; }
      __syncthreads();
      float M = aML[0]; int sel = aIL[0];
#pragma unroll
      for (int g2 = 1; g2 < 8; ++g2)
        if (aML[g2] > M) { M = aML[g2]; sel = aIL[g2]; }
      float S = 0.f;
#pragma unroll
      for (int g2 = 0; g2 < 8; ++g2) S += aSL[g2] * expf(aML[g2] - M);
      float lse = M + logf(S);
      if (t < RPT) {
        float v = lv[b * NP + n0 + t];
        out[((size_t)b * STEPS + step) * N + n0 + t] = (v == NEG_INF) ? OUT_NEG : (v - lse);
      }
      if (g == 0) {
        if (t == 0) {
          out[(size_t)B * STEPS * N + b * STEPS + step] = (float)sel;
          visited[b * NP + sel] = 1;
        }
        if (t < 128) {
          float e = emb[((size_t)b * N + sel) * D + t];
          prev_emb[b * 128 + t] = e;
          if (step == 0) first_emb[b * 128 + t] = e;
        }
      }
    }
    gg.sync();
  }
}

// ============================================================
extern "C" void kernel_launch(void* const* d_in, const int* in_sizes, int n_in,
                              void* d_out, int out_size, void* d_ws, size_t ws_size,
                              hipStream_t stream) {
  (void)in_sizes; (void)n_in; (void)out_size; (void)ws_size;
  const float* emb   = (const float*)d_in[0];
  const float* Wn    = (const float*)d_in[1];
  const float* Wf    = (const float*)d_in[2];
  const float* Wstep = (const float*)d_in[3];
  const float* Wout  = (const float*)d_in[4];
  const float* Wp    = (const float*)d_in[5];
  float* out = (float*)d_out;
  float* ws  = (float*)d_ws;

  int numCU = 256;
  hipDeviceGetAttribute(&numCU, hipDeviceAttributeMultiprocessorCount, 0);
  int maxB = 0;
  if (hipOccupancyMaxActiveBlocksPerMultiprocessor(
          &maxB, (const void*)decode_coop, 256, 0) != hipSuccess || maxB < 1)
    maxB = 1;
  int grid = maxB * numCU;
  if (grid > TASKS) grid = TASKS;

  void* args[] = {(void*)&emb, (void*)&Wn, (void*)&Wf, (void*)&Wstep,
                  (void*)&Wout, (void*)&Wp, (void*)&out, (void*)&ws};
  hipLaunchCooperativeKernel((const void*)decode_coop, dim3(grid), dim3(256),
                             args, 0, stream);
}

// Round 9
// 4748.551 us; speedup vs baseline: 3.0902x; 3.0902x over previous
//
#include <hip/hip_runtime.h>
#include <math.h>

#define B 128
#define N 1000
#define NP 1024
#define D 128
#define STEPS 64
#define NEG_INF (-INFINITY)
#define OUT_NEG (-1.0e30f)   // finite stand-in for -inf in OUTPUT only

// ---------------- ws layout (floats) ----------------
// fcPart    : B*8*128
// fixed_ctx : B*D
// mE, sE    : B*8*8      per-(b,g,head) softmax partial max / sumexp
// waE       : B*8*1024   per-(b,g): weighted-emb partial [h][d]
// qkW       : B*1024     per-b back-projected scaled query [h][d]
// first_emb : B*D
// visited   : B*NP ints

// ============================================================
// fixed_ctx phase 1 + 2 (round-7 proven)
// ============================================================
__global__ __launch_bounds__(256)
void fixed_part(const float* __restrict__ emb, float* __restrict__ fcPart) {
  const int b = blockIdx.x >> 3, g = blockIdx.x & 7;
  const int t = threadIdx.x, d = t & 127, half = t >> 7;
  __shared__ float part[256];
  float s = 0.f;
  for (int i = half; i < 125; i += 2)
    s += emb[((size_t)b * N + g * 125 + i) * D + d];
  part[t] = s;
  __syncthreads();
  if (t < 128) fcPart[(size_t)(b * 8 + g) * 128 + t] = part[t] + part[t + 128];
}

__global__ __launch_bounds__(128)
void fixed_combine(const float* __restrict__ fcPart, const float* __restrict__ Wf,
                   float* __restrict__ fixed_ctx) {
  const int b = blockIdx.x, t = threadIdx.x;
  __shared__ float meanL[128];
  float s = 0.f;
  for (int g = 0; g < 8; ++g) s += fcPart[(size_t)(b * 8 + g) * 128 + t];
  meanL[t] = s * (1.0f / 1000.0f);
  __syncthreads();
  float a = 0.f;
  for (int k = 0; k < 128; ++k) a += meanL[k] * Wf[k * 128 + t];
  fixed_ctx[b * 128 + t] = a;
}

// ============================================================
// prep0: per b, step-0 query from placeholder ctx: q = fixed + Wp@Wstep;
// qk[h][d] = 0.25 * sum_k q[h*16+k] * WnK[d][h*16+k]
// ============================================================
__global__ __launch_bounds__(256)
void prep0(const float* __restrict__ Wn, const float* __restrict__ Wstep,
           const float* __restrict__ Wp, const float* __restrict__ fixed_ctx,
           float* __restrict__ qkW) {
  const int b = blockIdx.x, t = threadIdx.x;
  __shared__ float qL[128];
  if (t < 128) {
    float a = fixed_ctx[b * 128 + t];
    for (int i = 0; i < 256; ++i) a += Wp[i] * Wstep[i * 128 + t];
    qL[t] = a;
  }
  __syncthreads();
#pragma unroll
  for (int u = 0; u < 4; ++u) {
    int idx = t + u * 256;
    int h = idx >> 7, d = idx & 127;
    float a = 0.f;
#pragma unroll
    for (int k = 0; k < 16; ++k) a += qL[h * 16 + k] * Wn[(size_t)d * 384 + h * 16 + k];
    qkW[(size_t)b * 1024 + idx] = a * 0.25f;
  }
}

// ============================================================
// glimpseE: grid B*8, block 256 (4 waves). Per (b,g): 128 rows.
// Reads precomputed qk (no weight reads). Two-pass softmax (r7-proven),
// writes mE/sE/waE partials. Only READS sequential state.
// ============================================================
__global__ __launch_bounds__(256)
void glimpseE(const float* __restrict__ emb, const float* __restrict__ qkW,
              const int* __restrict__ visited,
              float* __restrict__ mE, float* __restrict__ sE, float* __restrict__ waE) {
  const int b = blockIdx.x >> 3, g = blockIdx.x & 7;
  const int t = threadIdx.x, lane = t & 63, wv = t >> 6;
  const int r = (lane >> 4) & 3, c = lane & 15;

  __shared__ float qkL[1024];
  __shared__ float cB[1024];        // [h][nl] compat -> p
  __shared__ float waW[4][1024];    // wave partials
  __shared__ float mhL[8], shL[8];

#pragma unroll
  for (int u = 0; u < 4; ++u) {
    int idx = t + u * 256;
    qkL[idx] = qkW[(size_t)b * 1024 + idx];
  }
  __syncthreads();

  float qkr[8][8];
#pragma unroll
  for (int h = 0; h < 8; ++h)
#pragma unroll
    for (int j = 0; j < 8; ++j) qkr[h][j] = qkL[h * 128 + c * 8 + j];

  const float4* emb4 = (const float4*)emb;

  // ---- pass 1: compat ----
  for (int it = 0; it < 8; ++it) {
    int nl = it * 16 + wv * 4 + r;          // 0..127
    int n = g * 128 + nl;
    float4 e0 = make_float4(0.f, 0.f, 0.f, 0.f), e1 = e0;
    if (n < N) {
      e0 = emb4[((size_t)b * N + n) * 32 + c * 2];
      e1 = emb4[((size_t)b * N + n) * 32 + c * 2 + 1];
    }
    float s[8];
#pragma unroll
    for (int h = 0; h < 8; ++h) {
      s[h] = qkr[h][0] * e0.x + qkr[h][1] * e0.y + qkr[h][2] * e0.z + qkr[h][3] * e0.w
           + qkr[h][4] * e1.x + qkr[h][5] * e1.y + qkr[h][6] * e1.z + qkr[h][7] * e1.w;
    }
#pragma unroll
    for (int off = 1; off <= 8; off <<= 1)
#pragma unroll
      for (int h = 0; h < 8; ++h) s[h] += __shfl_xor(s[h], off);
    if (c == 0) {
      bool vis = (n >= N) || (visited[b * NP + n] != 0);
#pragma unroll
      for (int h = 0; h < 8; ++h) cB[h * 128 + nl] = vis ? NEG_INF : s[h];
    }
  }
  __syncthreads();

  // ---- per-head max ----
#pragma unroll
  for (int u = 0; u < 2; ++u) {
    int h = wv * 2 + u;
    float m = fmaxf(cB[h * 128 + lane], cB[h * 128 + lane + 64]);
#pragma unroll
    for (int off = 1; off <= 32; off <<= 1) m = fmaxf(m, __shfl_xor(m, off));
    if (lane == 0) mhL[h] = m;
  }
  __syncthreads();
  // ---- exp in place ----
#pragma unroll
  for (int u = 0; u < 4; ++u) {
    int idx = t + u * 256;
    float v = cB[idx];
    cB[idx] = (v == NEG_INF) ? 0.f : expf(v - mhL[idx >> 7]);
  }
  __syncthreads();
  // ---- per-head sum ----
#pragma unroll
  for (int u = 0; u < 2; ++u) {
    int h = wv * 2 + u;
    float s = cB[h * 128 + lane] + cB[h * 128 + lane + 64];
#pragma unroll
    for (int off = 1; off <= 32; off <<= 1) s += __shfl_xor(s, off);
    if (lane == 0) shL[h] = s;
  }

  // ---- pass 2: weighted emb ----
  float wa[8][8];
#pragma unroll
  for (int h = 0; h < 8; ++h)
#pragma unroll
    for (int j = 0; j < 8; ++j) wa[h][j] = 0.f;
  for (int it = 0; it < 8; ++it) {
    int nl = it * 16 + wv * 4 + r;
    int n = g * 128 + nl;
    if (n < N) {
      float4 e0 = emb4[((size_t)b * N + n) * 32 + c * 2];
      float4 e1 = emb4[((size_t)b * N + n) * 32 + c * 2 + 1];
#pragma unroll
      for (int h = 0; h < 8; ++h) {
        float p = cB[h * 128 + nl];
        wa[h][0] += p * e0.x; wa[h][1] += p * e0.y;
        wa[h][2] += p * e0.z; wa[h][3] += p * e0.w;
        wa[h][4] += p * e1.x; wa[h][5] += p * e1.y;
        wa[h][6] += p * e1.z; wa[h][7] += p * e1.w;
      }
    }
  }
#pragma unroll
  for (int h = 0; h < 8; ++h)
#pragma unroll
    for (int j = 0; j < 8; ++j) {
      wa[h][j] += __shfl_xor(wa[h][j], 16);
      wa[h][j] += __shfl_xor(wa[h][j], 32);
    }
  if (lane < 16) {
#pragma unroll
    for (int h = 0; h < 8; ++h)
#pragma unroll
      for (int j = 0; j < 8; ++j) waW[wv][h * 128 + c * 8 + j] = wa[h][j];
  }
  __syncthreads();
#pragma unroll
  for (int u = 0; u < 4; ++u) {
    int idx = t + u * 256;
    waE[(size_t)(blockIdx.x) * 1024 + idx] =
        waW[0][idx] + waW[1][idx] + waW[2][idx] + waW[3][idx];
  }
  if (t < 8) { mE[blockIdx.x * 8 + t] = mhL[t]; sE[blockIdx.x * 8 + t] = shL[t]; }
}

// ============================================================
// logitsF: grid B, block 1024 (16 waves). Merge partials -> weN -> heads ->
// glimpse -> lq; logits over 1024 rows via lq.emb (n-parallel, 16 waves);
// argmax/lse/out/visited/first_emb; then NEXT step's ctx->q->qk.
// ALL sequential state lives here.
// ============================================================
__global__ __launch_bounds__(1024)
void logitsF(const float* __restrict__ emb, const float* __restrict__ Wn,
             const float* __restrict__ Wout, const float* __restrict__ Wstep,
             const float* __restrict__ fixed_ctx,
             const float* __restrict__ mE, const float* __restrict__ sE,
             const float* __restrict__ waE,
             int* __restrict__ visited, float* __restrict__ first_emb,
             float* __restrict__ qkW, float* __restrict__ out, int step) {
  const int b = blockIdx.x;
  const int t = threadIdx.x;
  const int lane = t & 63, wid = t >> 6;        // wid 0..15
  const int c = lane & 15, rr = (lane >> 4) & 3;

  __shared__ float fH[64];       // [g][h]
  __shared__ float invS[8];
  __shared__ float weN[1024];    // [h][d]
  __shared__ float headsL[128];
  __shared__ float glL[128];
  __shared__ float lqL[128];
  __shared__ float lvL[1024];
  __shared__ float ctxL[256];
  __shared__ float qL2[128];
  __shared__ float redV[4];
  __shared__ int   redI[4];
  __shared__ float mS;
  __shared__ int   selS;

  // ---- merge softmax partials ----
  if (t < 8) {
    float M = NEG_INF;
    for (int g = 0; g < 8; ++g) M = fmaxf(M, mE[(b * 8 + g) * 8 + t]);
    float S = 0.f;
    for (int g = 0; g < 8; ++g) {
      float f = expf(mE[(b * 8 + g) * 8 + t] - M);
      fH[g * 8 + t] = f;
      S += sE[(b * 8 + g) * 8 + t] * f;
    }
    invS[t] = 1.0f / S;
  }
  __syncthreads();
  {
    int h = t >> 7;
    float w = 0.f;
    for (int g = 0; g < 8; ++g) w += waE[(size_t)(b * 8 + g) * 1024 + t] * fH[g * 8 + h];
    weN[t] = w * invS[h];
  }
  __syncthreads();

  // ---- heads (8 threads per output, 16 d each) ----
  {
    int o = t >> 3, sl = t & 7, h = o >> 4;
    float a = 0.f;
#pragma unroll
    for (int dd = 0; dd < 16; ++dd) {
      int d = sl * 16 + dd;
      a += weN[h * 128 + d] * Wn[(size_t)d * 384 + 128 + o];
    }
    a += __shfl_xor(a, 1); a += __shfl_xor(a, 2); a += __shfl_xor(a, 4);
    if (sl == 0) headsL[o] = a;
  }
  __syncthreads();
  // ---- glimpse ----
  {
    int o = t >> 3, sl = t & 7;
    float a = 0.f;
#pragma unroll
    for (int kk = 0; kk < 16; ++kk) {
      int k = sl * 16 + kk;
      a += headsL[k] * Wout[k * 128 + o];
    }
    a += __shfl_xor(a, 1); a += __shfl_xor(a, 2); a += __shfl_xor(a, 4);
    if (sl == 0) glL[o] = a;
  }
  __syncthreads();
  // ---- lq[d] = (1/sqrt(D)) * sum_e glL[e] * W3[d][e] ----
  {
    int o = t >> 3, sl = t & 7;
    float a = 0.f;
#pragma unroll
    for (int ee = 0; ee < 16; ++ee) {
      int e = sl * 16 + ee;
      a += glL[e] * Wn[(size_t)o * 384 + 256 + e];
    }
    a += __shfl_xor(a, 1); a += __shfl_xor(a, 2); a += __shfl_xor(a, 4);
    if (sl == 0) lqL[o] = a * 0.08838834764831845f;
  }
  __syncthreads();

  // ---- logits over 1024 rows (16 waves x 4 rows x 16 iters) ----
  {
    float lq0[8];
#pragma unroll
    for (int j = 0; j < 8; ++j) lq0[j] = lqL[c * 8 + j];
    const float4* emb4 = (const float4*)emb;
    for (int it = 0; it < 16; ++it) {
      int nl = it * 64 + wid * 4 + rr;        // 0..1023 unique
      float4 e0 = make_float4(0.f, 0.f, 0.f, 0.f), e1 = e0;
      if (nl < N) {
        e0 = emb4[((size_t)b * N + nl) * 32 + c * 2];
        e1 = emb4[((size_t)b * N + nl) * 32 + c * 2 + 1];
      }
      float s = lq0[0] * e0.x + lq0[1] * e0.y + lq0[2] * e0.z + lq0[3] * e0.w
              + lq0[4] * e1.x + lq0[5] * e1.y + lq0[6] * e1.z + lq0[7] * e1.w;
#pragma unroll
      for (int off = 1; off <= 8; off <<= 1) s += __shfl_xor(s, off);
      if (c == 0) {
        bool vis = (nl >= N) || (visited[b * NP + nl] != 0);
        lvL[nl] = vis ? NEG_INF : 10.f * tanhf(s);
      }
    }
  }
  __syncthreads();

  // ---- argmax + lse on first 256 threads (round-2 proven) ----
  float lv[4];
  int ok[4];
  if (t < 256) {
#pragma unroll
    for (int j = 0; j < 4; ++j) {
      float v = lvL[t * 4 + j];
      lv[j] = v;
      ok[j] = (v != NEG_INF);
    }
    float bv = lv[0];
    int bi = t * 4;
#pragma unroll
    for (int j = 1; j < 4; ++j)
      if (lv[j] > bv) { bv = lv[j]; bi = t * 4 + j; }
#pragma unroll
    for (int off = 32; off >= 1; off >>= 1) {
      float ov = __shfl_xor(bv, off);
      int oi = __shfl_xor(bi, off);
      if (ov > bv || (ov == bv && oi < bi)) { bv = ov; bi = oi; }
    }
    if (lane == 0) { redV[wid] = bv; redI[wid] = bi; }
  }
  __syncthreads();
  if (t == 0) {
    float mv = redV[0]; int mi = redI[0];
    for (int w = 1; w < 4; ++w)
      if (redV[w] > mv || (redV[w] == mv && redI[w] < mi)) { mv = redV[w]; mi = redI[w]; }
    mS = mv; selS = mi;
  }
  __syncthreads();
  const float m = mS;

  float se = 0.f;
  if (t < 256) {
#pragma unroll
    for (int j = 0; j < 4; ++j) if (ok[j]) se += expf(lv[j] - m);
#pragma unroll
    for (int off = 32; off >= 1; off >>= 1) se += __shfl_xor(se, off);
  }
  __syncthreads();
  if (t < 256 && lane == 0) redV[wid] = se;
  __syncthreads();
  const float lse = m + logf(redV[0] + redV[1] + redV[2] + redV[3]);
  const int sel = selS;

  if (t < 250) {
    float4 o;
    o.x = ok[0] ? (lv[0] - lse) : OUT_NEG;
    o.y = ok[1] ? (lv[1] - lse) : OUT_NEG;
    o.z = ok[2] ? (lv[2] - lse) : OUT_NEG;
    o.w = ok[3] ? (lv[3] - lse) : OUT_NEG;
    ((float4*)(out + ((size_t)b * STEPS + step) * N))[t] = o;
  }
  if (t == 0) {
    out[(size_t)B * STEPS * N + b * STEPS + step] = (float)sel;
    visited[b * NP + sel] = 1;
  }

  // ---- next step's ctx -> q -> qk ----
  if (t < 256) {
    float v;
    if (t < 128) {
      if (step == 0) {
        v = emb[((size_t)b * N + sel) * D + t];
        first_emb[b * 128 + t] = v;
      } else {
        v = first_emb[b * 128 + t];
      }
    } else {
      v = emb[((size_t)b * N + sel) * D + (t - 128)];
    }
    ctxL[t] = v;
  }
  __syncthreads();
  {
    int o = t >> 3, sl = t & 7;
    float a = 0.f;
#pragma unroll
    for (int ii = 0; ii < 32; ++ii) {
      int i = sl * 32 + ii;
      a += ctxL[i] * Wstep[i * 128 + o];
    }
    a += __shfl_xor(a, 1); a += __shfl_xor(a, 2); a += __shfl_xor(a, 4);
    if (sl == 0) qL2[o] = fixed_ctx[b * 128 + o] + a;
  }
  __syncthreads();
  {
    int h = t >> 7, d = t & 127;
    float a = 0.f;
#pragma unroll
    for (int k = 0; k < 16; ++k) a += qL2[h * 16 + k] * Wn[(size_t)d * 384 + h * 16 + k];
    qkW[(size_t)b * 1024 + t] = a * 0.25f;
  }
}

// ============================================================
extern "C" void kernel_launch(void* const* d_in, const int* in_sizes, int n_in,
                              void* d_out, int out_size, void* d_ws, size_t ws_size,
                              hipStream_t stream) {
  (void)in_sizes; (void)n_in; (void)out_size; (void)ws_size;
  const float* emb   = (const float*)d_in[0];
  const float* Wn    = (const float*)d_in[1];
  const float* Wf    = (const float*)d_in[2];
  const float* Wstep = (const float*)d_in[3];
  const float* Wout  = (const float*)d_in[4];
  const float* Wp    = (const float*)d_in[5];
  float* out = (float*)d_out;
  float* ws  = (float*)d_ws;

  float* fcPart    = ws;
  float* fixed_ctx = fcPart + (size_t)B * 8 * 128;
  float* mEp       = fixed_ctx + (size_t)B * D;
  float* sEp       = mEp + (size_t)B * 8 * 8;
  float* waE       = sEp + (size_t)B * 8 * 8;
  float* qkW       = waE + (size_t)B * 8 * 1024;
  float* first_emb = qkW + (size_t)B * 1024;
  int*   visited   = (int*)(first_emb + (size_t)B * D);

  hipMemsetAsync(visited, 0, (size_t)B * NP * sizeof(int), stream);
  fixed_part<<<B * 8, 256, 0, stream>>>(emb, fcPart);
  fixed_combine<<<B, 128, 0, stream>>>(fcPart, Wf, fixed_ctx);
  prep0<<<B, 256, 0, stream>>>(Wn, Wstep, Wp, fixed_ctx, qkW);
  for (int s = 0; s < STEPS; ++s) {
    glimpseE<<<B * 8, 256, 0, stream>>>(emb, qkW, visited, mEp, sEp, waE);
    logitsF<<<B, 1024, 0, stream>>>(emb, Wn, Wout, Wstep, fixed_ctx,
                                    mEp, sEp, waE, visited, first_emb,
                                    qkW, out, s);
  }
}

// Round 10
// 3968.119 us; speedup vs baseline: 3.6979x; 1.1967x over previous
//
#include <hip/hip_runtime.h>
#include <math.h>

#define B 128
#define N 1000
#define NP 1024
#define D 128
#define STEPS 64
#define NEG_INF (-INFINITY)
#define OUT_NEG (-1.0e30f)   // finite stand-in for -inf in OUTPUT only

// ---------------- ws layout (floats) ----------------
// embT      : B*128*1024   transposed embeddings [b][d][n]
// fcPart    : B*8*128
// fixed_ctx : B*D
// qkW       : B*1024       back-projected scaled query [h][d]
// mQ, sQ    : B*4*8        per-(b,quarter,head) softmax partial max / sumexp
// waQ       : B*4*1024     per-(b,quarter): weighted-emb partial [h][d] (scaled to mQ)
// first_emb : B*D
// visited   : B*NP ints

// ============================================================
// transposeE: emb (B,1000,128) -> embT (B,128,1024). grid B*8, block 256.
// 125 rows per block, LDS-tiled in 32/32/32/29-row subtiles.
// ============================================================
__global__ __launch_bounds__(256)
void transposeE(const float* __restrict__ emb, float* __restrict__ embT) {
  const int b = blockIdx.x >> 3, ng = blockIdx.x & 7;
  const int t = threadIdx.x;
  const int n0 = ng * 125;
  __shared__ float tile[32 * 133];

  int r0 = 0;
  for (int s = 0; s < 4; ++s) {
    const int cnt = (s < 3) ? 32 : 29;
    __syncthreads();
    for (int idx = t; idx < cnt * 128; idx += 256) {
      int r = idx >> 7, d = idx & 127;
      tile[r * 133 + d] = emb[((size_t)b * 1000 + n0 + r0 + r) * 128 + d];
    }
    __syncthreads();
    {
      int nl = t & 31, dg = t >> 5;          // dg 0..7
      if (nl < cnt) {
#pragma unroll
        for (int dd = 0; dd < 16; ++dd) {
          int d = dg * 16 + dd;
          embT[((size_t)b * 128 + d) * 1024 + n0 + r0 + nl] = tile[nl * 133 + d];
        }
      }
    }
    r0 += cnt;
  }
}

// ============================================================
// fixed_ctx phase 1 + 2 (round-9 proven)
// ============================================================
__global__ __launch_bounds__(256)
void fixed_part(const float* __restrict__ emb, float* __restrict__ fcPart) {
  const int b = blockIdx.x >> 3, g = blockIdx.x & 7;
  const int t = threadIdx.x, d = t & 127, half = t >> 7;
  __shared__ float part[256];
  float s = 0.f;
  for (int i = half; i < 125; i += 2)
    s += emb[((size_t)b * N + g * 125 + i) * D + d];
  part[t] = s;
  __syncthreads();
  if (t < 128) fcPart[(size_t)(b * 8 + g) * 128 + t] = part[t] + part[t + 128];
}

__global__ __launch_bounds__(128)
void fixed_combine(const float* __restrict__ fcPart, const float* __restrict__ Wf,
                   float* __restrict__ fixed_ctx) {
  const int b = blockIdx.x, t = threadIdx.x;
  __shared__ float meanL[128];
  float s = 0.f;
  for (int g = 0; g < 8; ++g) s += fcPart[(size_t)(b * 8 + g) * 128 + t];
  meanL[t] = s * (1.0f / 1000.0f);
  __syncthreads();
  float a = 0.f;
  for (int k = 0; k < 128; ++k) a += meanL[k] * Wf[k * 128 + t];
  fixed_ctx[b * 128 + t] = a;
}

// ============================================================
// prep0 (round-9 proven): step-0 qk from placeholder ctx.
// ============================================================
__global__ __launch_bounds__(256)
void prep0(const float* __restrict__ Wn, const float* __restrict__ Wstep,
           const float* __restrict__ Wp, const float* __restrict__ fixed_ctx,
           float* __restrict__ qkW) {
  const int b = blockIdx.x, t = threadIdx.x;
  __shared__ float qL[128];
  if (t < 128) {
    float a = fixed_ctx[b * 128 + t];
    for (int i = 0; i < 256; ++i) a += Wp[i] * Wstep[i * 128 + t];
    qL[t] = a;
  }
  __syncthreads();
#pragma unroll
  for (int u = 0; u < 4; ++u) {
    int idx = t + u * 256;
    int h = idx >> 7, d = idx & 127;
    float a = 0.f;
#pragma unroll
    for (int k = 0; k < 16; ++k) a += qL[h * 16 + k] * Wn[(size_t)d * 384 + h * 16 + k];
    qkW[(size_t)b * 1024 + idx] = a * 0.25f;
  }
}

// ============================================================
// glimpseT: grid B*4, block 256 (4 waves). Quarter q owns rows
// [q*256, q*256+rows) with rows = 256 (q<3) or 232 (q=3).
// Pass1: thread-per-row compat via embT (coalesced) + uniform qk float4
// broadcasts — NO cross-lane shuffles. Block softmax (one reduce).
// Pass2: thread-per-(h,d) weighted sum via per-lane float4 embT reads +
// uniform b128 p broadcasts — NO reduction. Writes mQ/sQ/waQ partials.
// ============================================================
__global__ __launch_bounds__(256)
void glimpseT(const float* __restrict__ embT, const float* __restrict__ qkW,
              const int* __restrict__ visited,
              float* __restrict__ mQ, float* __restrict__ sQ,
              float* __restrict__ waQ) {
  const int b = blockIdx.x >> 2, q = blockIdx.x & 3;
  const int rows = (q < 3) ? 256 : 232;
  const int t = threadIdx.x, lane = t & 63, wv = t >> 6;

  __shared__ float qkL[1024];
  __shared__ float pB[8 * 264];    // compat -> p; stride 264 (16B-aligned)
  __shared__ float mhL[8], shL[8];

#pragma unroll
  for (int u = 0; u < 4; ++u)
    qkL[t + u * 256] = qkW[(size_t)b * 1024 + t + u * 256];
  __syncthreads();

  const int n = q * 256 + t;
  const float* eT = embT + (size_t)b * 128 * 1024;

  // ---- pass 1: compat (thread-per-row) ----
  float acc[8] = {0.f, 0.f, 0.f, 0.f, 0.f, 0.f, 0.f, 0.f};
  if (t < rows) {
    for (int d4 = 0; d4 < 32; ++d4) {
      float e0 = eT[(size_t)(d4 * 4 + 0) * 1024 + n];
      float e1 = eT[(size_t)(d4 * 4 + 1) * 1024 + n];
      float e2 = eT[(size_t)(d4 * 4 + 2) * 1024 + n];
      float e3 = eT[(size_t)(d4 * 4 + 3) * 1024 + n];
#pragma unroll
      for (int h = 0; h < 8; ++h) {
        float4 k4 = *(const float4*)&qkL[h * 128 + d4 * 4];
        acc[h] += k4.x * e0 + k4.y * e1 + k4.z * e2 + k4.w * e3;
      }
    }
  }
  bool vis = (t >= rows) || (visited[b * NP + n] != 0);
#pragma unroll
  for (int h = 0; h < 8; ++h) pB[h * 264 + t] = vis ? NEG_INF : acc[h];
  __syncthreads();

  // ---- per-head max (wave wv handles heads 2wv, 2wv+1) ----
#pragma unroll
  for (int u = 0; u < 2; ++u) {
    int h = wv * 2 + u;
    float m = fmaxf(fmaxf(pB[h * 264 + lane], pB[h * 264 + lane + 64]),
                    fmaxf(pB[h * 264 + lane + 128], pB[h * 264 + lane + 192]));
#pragma unroll
    for (int off = 1; off <= 32; off <<= 1) m = fmaxf(m, __shfl_xor(m, off));
    if (lane == 0) mhL[h] = m;
  }
  __syncthreads();
  // ---- exp in place ----
#pragma unroll
  for (int h = 0; h < 8; ++h) {
    float v = pB[h * 264 + t];
    pB[h * 264 + t] = (v == NEG_INF) ? 0.f : expf(v - mhL[h]);
  }
  __syncthreads();
  // ---- per-head sum ----
#pragma unroll
  for (int u = 0; u < 2; ++u) {
    int h = wv * 2 + u;
    float s = pB[h * 264 + lane] + pB[h * 264 + lane + 64]
            + pB[h * 264 + lane + 128] + pB[h * 264 + lane + 192];
#pragma unroll
    for (int off = 1; off <= 32; off <<= 1) s += __shfl_xor(s, off);
    if (lane == 0) shL[h] = s;
  }
  __syncthreads();
  if (t < 8) { mQ[(b * 4 + q) * 8 + t] = mhL[t]; sQ[(b * 4 + q) * 8 + t] = shL[t]; }

  // ---- pass 2: weighted emb, thread owns (hq*4+u, d) ----
  const int d = t & 127, hq = t >> 7;
  float wa[4] = {0.f, 0.f, 0.f, 0.f};
  const float* eTd = eT + (size_t)d * 1024 + q * 256;
  const int n4cnt = rows >> 2;          // 64 or 58
  for (int n4 = 0; n4 < n4cnt; ++n4) {
    float4 ev = *(const float4*)(eTd + n4 * 4);
#pragma unroll
    for (int u = 0; u < 4; ++u) {
      int h = hq * 4 + u;
      float4 p4 = *(const float4*)&pB[h * 264 + n4 * 4];
      wa[u] += p4.x * ev.x + p4.y * ev.y + p4.z * ev.z + p4.w * ev.w;
    }
  }
#pragma unroll
  for (int u = 0; u < 4; ++u)
    waQ[(size_t)(b * 4 + q) * 1024 + (hq * 4 + u) * 128 + d] = wa[u];
}

// ============================================================
// logitsT: grid B, block 1024 (16 waves). Merge 4 quarter partials -> weN
// -> heads -> glimpse -> lq; logits thread-per-n via embT (coalesced,
// shuffle-free); argmax/lse/out/visited/first_emb; next step's qk.
// ALL sequential state lives here. (round-9 skeleton)
// ============================================================
__global__ __launch_bounds__(1024)
void logitsT(const float* __restrict__ emb, const float* __restrict__ embT,
             const float* __restrict__ Wn, const float* __restrict__ Wout,
             const float* __restrict__ Wstep, const float* __restrict__ fixed_ctx,
             const float* __restrict__ mQ, const float* __restrict__ sQ,
             const float* __restrict__ waQ,
             int* __restrict__ visited, float* __restrict__ first_emb,
             float* __restrict__ qkW, float* __restrict__ out, int step) {
  const int b = blockIdx.x;
  const int t = threadIdx.x;
  const int lane = t & 63, wid = t >> 6;

  __shared__ float eQL[32];      // [q][h]
  __shared__ float invS[8];
  __shared__ float weN[1024];    // [h][d]
  __shared__ float headsL[128];
  __shared__ float glL[128];
  __shared__ float lqL[128];
  __shared__ float lvL[1024];
  __shared__ float ctxL[256];
  __shared__ float qL2[128];
  __shared__ float redV[4];
  __shared__ int   redI[4];
  __shared__ float mS;
  __shared__ int   selS;

  // ---- merge 4 quarter softmax partials ----
  if (t < 8) {
    float M = NEG_INF;
    for (int qq = 0; qq < 4; ++qq) M = fmaxf(M, mQ[(b * 4 + qq) * 8 + t]);
    float S = 0.f;
    for (int qq = 0; qq < 4; ++qq) {
      float f = expf(mQ[(b * 4 + qq) * 8 + t] - M);
      eQL[qq * 8 + t] = f;
      S += sQ[(b * 4 + qq) * 8 + t] * f;
    }
    invS[t] = 1.0f / S;
  }
  __syncthreads();
  {
    int h = t >> 7;
    float w = 0.f;
    for (int qq = 0; qq < 4; ++qq)
      w += waQ[(size_t)(b * 4 + qq) * 1024 + t] * eQL[qq * 8 + h];
    weN[t] = w * invS[h];
  }
  __syncthreads();

  // ---- heads (8 threads per output, 16 d each) ----
  {
    int o = t >> 3, sl = t & 7, h = o >> 4;
    float a = 0.f;
#pragma unroll
    for (int dd = 0; dd < 16; ++dd) {
      int d = sl * 16 + dd;
      a += weN[h * 128 + d] * Wn[(size_t)d * 384 + 128 + o];
    }
    a += __shfl_xor(a, 1); a += __shfl_xor(a, 2); a += __shfl_xor(a, 4);
    if (sl == 0) headsL[o] = a;
  }
  __syncthreads();
  // ---- glimpse ----
  {
    int o = t >> 3, sl = t & 7;
    float a = 0.f;
#pragma unroll
    for (int kk = 0; kk < 16; ++kk) {
      int k = sl * 16 + kk;
      a += headsL[k] * Wout[k * 128 + o];
    }
    a += __shfl_xor(a, 1); a += __shfl_xor(a, 2); a += __shfl_xor(a, 4);
    if (sl == 0) glL[o] = a;
  }
  __syncthreads();
  // ---- lq[d] = (1/sqrt(D)) * sum_e glL[e] * W3[d][e] ----
  {
    int o = t >> 3, sl = t & 7;
    float a = 0.f;
#pragma unroll
    for (int ee = 0; ee < 16; ++ee) {
      int e = sl * 16 + ee;
      a += glL[e] * Wn[(size_t)o * 384 + 256 + e];
    }
    a += __shfl_xor(a, 1); a += __shfl_xor(a, 2); a += __shfl_xor(a, 4);
    if (sl == 0) lqL[o] = a * 0.08838834764831845f;
  }
  __syncthreads();

  // ---- logits: thread t owns n = t (coalesced embT, no shuffles) ----
  {
    const float* eTb = embT + (size_t)b * 128 * 1024;
    float lg = 0.f;
    for (int d4 = 0; d4 < 32; ++d4) {
      float4 lq4 = *(const float4*)&lqL[d4 * 4];
      lg += lq4.x * eTb[(size_t)(d4 * 4 + 0) * 1024 + t]
          + lq4.y * eTb[(size_t)(d4 * 4 + 1) * 1024 + t]
          + lq4.z * eTb[(size_t)(d4 * 4 + 2) * 1024 + t]
          + lq4.w * eTb[(size_t)(d4 * 4 + 3) * 1024 + t];
    }
    bool vis = (t >= N) || (visited[b * NP + t] != 0);
    lvL[t] = vis ? NEG_INF : 10.f * tanhf(lg);
  }
  __syncthreads();

  // ---- argmax + lse on first 256 threads (round-9 proven) ----
  float lv[4];
  int ok[4];
  if (t < 256) {
#pragma unroll
    for (int j = 0; j < 4; ++j) {
      float v = lvL[t * 4 + j];
      lv[j] = v;
      ok[j] = (v != NEG_INF);
    }
    float bv = lv[0];
    int bi = t * 4;
#pragma unroll
    for (int j = 1; j < 4; ++j)
      if (lv[j] > bv) { bv = lv[j]; bi = t * 4 + j; }
#pragma unroll
    for (int off = 32; off >= 1; off >>= 1) {
      float ov = __shfl_xor(bv, off);
      int oi = __shfl_xor(bi, off);
      if (ov > bv || (ov == bv && oi < bi)) { bv = ov; bi = oi; }
    }
    if (lane == 0) { redV[wid] = bv; redI[wid] = bi; }
  }
  __syncthreads();
  if (t == 0) {
    float mv = redV[0]; int mi = redI[0];
    for (int w = 1; w < 4; ++w)
      if (redV[w] > mv || (redV[w] == mv && redI[w] < mi)) { mv = redV[w]; mi = redI[w]; }
    mS = mv; selS = mi;
  }
  __syncthreads();
  const float m = mS;

  float se = 0.f;
  if (t < 256) {
#pragma unroll
    for (int j = 0; j < 4; ++j) if (ok[j]) se += expf(lv[j] - m);
#pragma unroll
    for (int off = 32; off >= 1; off >>= 1) se += __shfl_xor(se, off);
  }
  __syncthreads();
  if (t < 256 && lane == 0) redV[wid] = se;
  __syncthreads();
  const float lse = m + logf(redV[0] + redV[1] + redV[2] + redV[3]);
  const int sel = selS;

  if (t < 250) {
    float4 o;
    o.x = ok[0] ? (lv[0] - lse) : OUT_NEG;
    o.y = ok[1] ? (lv[1] - lse) : OUT_NEG;
    o.z = ok[2] ? (lv[2] - lse) : OUT_NEG;
    o.w = ok[3] ? (lv[3] - lse) : OUT_NEG;
    ((float4*)(out + ((size_t)b * STEPS + step) * N))[t] = o;
  }
  if (t == 0) {
    out[(size_t)B * STEPS * N + b * STEPS + step] = (float)sel;
    visited[b * NP + sel] = 1;
  }

  // ---- next step's ctx -> q -> qk (round-9 proven tail) ----
  if (t < 256) {
    float v;
    if (t < 128) {
      if (step == 0) {
        v = emb[((size_t)b * N + sel) * D + t];
        first_emb[b * 128 + t] = v;
      } else {
        v = first_emb[b * 128 + t];
      }
    } else {
      v = emb[((size_t)b * N + sel) * D + (t - 128)];
    }
    ctxL[t] = v;
  }
  __syncthreads();
  {
    int o = t >> 3, sl = t & 7;
    float a = 0.f;
#pragma unroll
    for (int ii = 0; ii < 32; ++ii) {
      int i = sl * 32 + ii;
      a += ctxL[i] * Wstep[i * 128 + o];
    }
    a += __shfl_xor(a, 1); a += __shfl_xor(a, 2); a += __shfl_xor(a, 4);
    if (sl == 0) qL2[o] = fixed_ctx[b * 128 + o] + a;
  }
  __syncthreads();
  {
    int h = t >> 7, d = t & 127;
    float a = 0.f;
#pragma unroll
    for (int k = 0; k < 16; ++k) a += qL2[h * 16 + k] * Wn[(size_t)d * 384 + h * 16 + k];
    qkW[(size_t)b * 1024 + t] = a * 0.25f;
  }
}

// ============================================================
extern "C" void kernel_launch(void* const* d_in, const int* in_sizes, int n_in,
                              void* d_out, int out_size, void* d_ws, size_t ws_size,
                              hipStream_t stream) {
  (void)in_sizes; (void)n_in; (void)out_size; (void)ws_size;
  const float* emb   = (const float*)d_in[0];
  const float* Wn    = (const float*)d_in[1];
  const float* Wf    = (const float*)d_in[2];
  const float* Wstep = (const float*)d_in[3];
  const float* Wout  = (const float*)d_in[4];
  const float* Wp    = (const float*)d_in[5];
  float* out = (float*)d_out;
  float* ws  = (float*)d_ws;

  float* embT      = ws;
  float* fcPart    = embT + (size_t)B * 128 * 1024;
  float* fixed_ctx = fcPart + (size_t)B * 8 * 128;
  float* qkW       = fixed_ctx + (size_t)B * D;
  float* mQ        = qkW + (size_t)B * 1024;
  float* sQ        = mQ + (size_t)B * 4 * 8;
  float* waQ       = sQ + (size_t)B * 4 * 8;
  float* first_emb = waQ + (size_t)B * 4 * 1024;
  int*   visited   = (int*)(first_emb + (size_t)B * D);

  hipMemsetAsync(visited, 0, (size_t)B * NP * sizeof(int), stream);
  transposeE<<<B * 8, 256, 0, stream>>>(emb, embT);
  fixed_part<<<B * 8, 256, 0, stream>>>(emb, fcPart);
  fixed_combine<<<B, 128, 0, stream>>>(fcPart, Wf, fixed_ctx);
  prep0<<<B, 256, 0, stream>>>(Wn, Wstep, Wp, fixed_ctx, qkW);
  for (int s = 0; s < STEPS; ++s) {
    glimpseT<<<B * 4, 256, 0, stream>>>(embT, qkW, visited, mQ, sQ, waQ);
    logitsT<<<B, 1024, 0, stream>>>(emb, embT, Wn, Wout, Wstep, fixed_ctx,
                                    mQ, sQ, waQ, visited, first_emb,
                                    qkW, out, s);
  }
}